// Round 3
// baseline (173.972 us; speedup 1.0000x reference)
//
#include <hip/hip_runtime.h>
#include <hip/hip_bf16.h>
#include <stdint.h>

// NTXentLoss: B=4096, D=512, N=8192, tau=0.07, out = scalar mean loss.
// loss_i = -sim[i, i^B] + M + log( sum_{j != i} exp(sim_ij - M) ),  M = 1/tau
// mean  = M + ( Sum_i log S_i  -  Sum_i pos_i ) / N
// (the reference's two -1e9 mask entries underflow to 0 in logsumexp).
//
// R3: BK=128 (4 K-iters, half the barrier drains, 64 MFMA per barrier per
// wave); pos reduced to a single atomic scalar; final reduction fused into
// ksim via last-block pattern (all cross-block data is device-scope atomics).

#define N_TOT   8192
#define B_HALF  4096
#define DDIM    512
#define INV_TAU 14.285714285714286f   // 1/0.07 == fixed logsumexp offset M
#define NBLK    2080                  // 64*65/2 upper-triangle 128x128 tiles

typedef __bf16 bf16x8 __attribute__((ext_vector_type(8)));
typedef __bf16 bf16x4 __attribute__((ext_vector_type(4)));
typedef float  floatx4 __attribute__((ext_vector_type(4)));

__device__ __forceinline__ void gl2lds16(const void* g, void* l) {
    __builtin_amdgcn_global_load_lds(
        (const __attribute__((address_space(1))) void*)g,
        (__attribute__((address_space(3))) void*)l, 16, 0, 0);
}

// ---------------- kernel 1: normalize rows, fp32 -> bf16 z; zero accum ------
__global__ __launch_bounds__(256) void knorm(const float* __restrict__ anchor,
                                             const float* __restrict__ positive,
                                             __bf16* __restrict__ z,
                                             float* __restrict__ row_sums,
                                             float* __restrict__ pos_total,
                                             unsigned* __restrict__ counter) {
    const int row  = blockIdx.x * 4 + (threadIdx.x >> 6);
    const int lane = threadIdx.x & 63;
    if (lane == 0) row_sums[row] = 0.0f;
    if (blockIdx.x == 0 && threadIdx.x == 0) { pos_total[0] = 0.0f; counter[0] = 0u; }
    const float* src = (row < B_HALF) ? (anchor + (size_t)row * DDIM)
                                      : (positive + (size_t)(row - B_HALF) * DDIM);
    float4 v0 = ((const float4*)src)[lane];
    float4 v1 = ((const float4*)src)[lane + 64];
    float ss = v0.x*v0.x + v0.y*v0.y + v0.z*v0.z + v0.w*v0.w
             + v1.x*v1.x + v1.y*v1.y + v1.z*v1.z + v1.w*v1.w;
    #pragma unroll
    for (int m = 1; m < 64; m <<= 1) ss += __shfl_xor(ss, m, 64);
    const float inv = 1.0f / fmaxf(sqrtf(ss), 1e-8f);
    bf16x4 o0, o1;
    o0[0] = (__bf16)(v0.x*inv); o0[1] = (__bf16)(v0.y*inv);
    o0[2] = (__bf16)(v0.z*inv); o0[3] = (__bf16)(v0.w*inv);
    o1[0] = (__bf16)(v1.x*inv); o1[1] = (__bf16)(v1.y*inv);
    o1[2] = (__bf16)(v1.z*inv); o1[3] = (__bf16)(v1.w*inv);
    bf16x4* dst = (bf16x4*)(z + (size_t)row * DDIM);
    dst[lane]      = o0;
    dst[lane + 64] = o1;
}

// ---------------- kernel 2: upper-triangle sim tiles + fused everything -----
// 2080 blocks (rt <= ct), 4 waves; wave = 64x64 C via 4x4 16x16x32 frags.
// BK=128: LDS 2 x 32 KB, rotation-swizzled mod 16 (conflict-free ds_read_b128,
// global_load_lds keeps wave-uniform base + lane*16).
__global__ __launch_bounds__(256, 2) void ksim(const __bf16* __restrict__ z,
                                               float* __restrict__ row_sums,
                                               float* __restrict__ pos_total,
                                               unsigned* __restrict__ counter,
                                               float* __restrict__ out) {
    int rem = blockIdx.x, rt = 0;
    while (rem >= 64 - rt) { rem -= 64 - rt; rt++; }
    const int ct = rt + rem;
    const bool diag = (rt == ct);
    const bool posb = (ct == rt + 32);

    const int r0 = rt * 128, c0 = ct * 128;
    const int tid  = threadIdx.x;
    const int w    = tid >> 6, lane = tid & 63;
    const int quad = lane >> 4, nlo = lane & 15;
    const int wrow = (w >> 1) * 64, wcol = (w & 1) * 64;

    __shared__ __align__(16) char smem[65536];
    char* As = smem;            // 32 KB: 128 rows x 256 B
    char* Bs = smem + 32768;    // 32 KB
    const char* Bbase = diag ? As : Bs;

    floatx4 acc[4][4];
    #pragma unroll
    for (int a = 0; a < 4; a++)
        #pragma unroll
        for (int b = 0; b < 4; b++) acc[a][b] = (floatx4){0.f, 0.f, 0.f, 0.f};

    const int srow = lane >> 4;   // row within a 4-row staging group
    const int p    = lane & 15;   // physical 16B chunk within 256B row

    for (int kb = 0; kb < DDIM; kb += 128) {
        #pragma unroll
        for (int it = 0; it < 8; it++) {
            const int c  = w * 8 + it;          // 4-row group id, 0..31
            const int rr = c * 4 + srow;        // tile row 0..127
            const int lc = (p - rr) & 15;       // logical chunk stored at phys p
            gl2lds16(z + (size_t)(r0 + rr) * DDIM + kb + lc * 8, As + c * 1024);
            if (!diag)
                gl2lds16(z + (size_t)(c0 + rr) * DDIM + kb + lc * 8, Bs + c * 1024);
        }
        __syncthreads();

        #pragma unroll
        for (int ks = 0; ks < 4; ks++) {
            bf16x8 af[4], bfr[4];
            #pragma unroll
            for (int mi = 0; mi < 4; mi++) {
                const int rr = wrow + mi * 16 + nlo;
                const int pc = (ks * 4 + quad + rr) & 15;
                af[mi] = *(const bf16x8*)(As + rr * 256 + pc * 16);
            }
            #pragma unroll
            for (int ni = 0; ni < 4; ni++) {
                const int rr = wcol + ni * 16 + nlo;
                const int pc = (ks * 4 + quad + rr) & 15;
                bfr[ni] = *(const bf16x8*)(Bbase + rr * 256 + pc * 16);
            }
            #pragma unroll
            for (int mi = 0; mi < 4; mi++)
                #pragma unroll
                for (int ni = 0; ni < 4; ni++)
                    acc[mi][ni] = __builtin_amdgcn_mfma_f32_16x16x32_bf16(
                        af[mi], bfr[ni], acc[mi][ni], 0, 0, 0);
        }
        __syncthreads();
    }

    // epilogue: C/D layout col = lane&15, row = quad*4 + reg
    if (diag) {
        #pragma unroll
        for (int mi = 0; mi < 4; mi++) {
            #pragma unroll
            for (int reg = 0; reg < 4; reg++) {
                const int i = r0 + wrow + mi * 16 + quad * 4 + reg;
                float rs = 0.f;
                #pragma unroll
                for (int ni = 0; ni < 4; ni++) {
                    const int j = c0 + wcol + ni * 16 + nlo;
                    const float e = __expf(acc[mi][ni][reg] * INV_TAU - INV_TAU);
                    rs += (j == i) ? 0.f : e;
                }
                rs += __shfl_xor(rs, 1, 64);
                rs += __shfl_xor(rs, 2, 64);
                rs += __shfl_xor(rs, 4, 64);
                rs += __shfl_xor(rs, 8, 64);
                if (nlo == 0) atomicAdd(&row_sums[i], rs);
            }
        }
    } else {
        float cs[4] = {0.f, 0.f, 0.f, 0.f};   // per-lane col partials
        float ppos = 0.f;
        #pragma unroll
        for (int mi = 0; mi < 4; mi++) {
            #pragma unroll
            for (int reg = 0; reg < 4; reg++) {
                const int i = r0 + wrow + mi * 16 + quad * 4 + reg;
                const int ipos = i ^ B_HALF;
                float rs = 0.f;
                #pragma unroll
                for (int ni = 0; ni < 4; ni++) {
                    const int j = c0 + wcol + ni * 16 + nlo;
                    const float sim = acc[mi][ni][reg] * INV_TAU;
                    const float e = __expf(sim - INV_TAU);
                    if (posb && j == ipos) ppos += 2.0f * sim; // pair counted for i and i^B
                    rs += e;
                    cs[ni] += e;
                }
                rs += __shfl_xor(rs, 1, 64);
                rs += __shfl_xor(rs, 2, 64);
                rs += __shfl_xor(rs, 4, 64);
                rs += __shfl_xor(rs, 8, 64);
                if (nlo == 0) atomicAdd(&row_sums[i], rs);
            }
        }
        #pragma unroll
        for (int ni = 0; ni < 4; ni++) {
            float c = cs[ni];
            c += __shfl_xor(c, 16, 64);
            c += __shfl_xor(c, 32, 64);
            if (quad == 0)
                atomicAdd(&row_sums[c0 + wcol + ni * 16 + nlo], c);
        }
        if (posb) {
            #pragma unroll
            for (int m = 1; m < 64; m <<= 1) ppos += __shfl_xor(ppos, m, 64);
            if (lane == 0) atomicAdd(pos_total, ppos);
        }
    }

    // ---- last-block final reduction (replaces kfinal dispatch) ----
    __shared__ unsigned last_flag;
    __syncthreads();                 // drains each wave's atomics (vmcnt(0) before s_barrier)
    if (tid == 0) {
        __threadfence();
        last_flag = (atomicAdd(counter, 1u) == NBLK - 1) ? 1u : 0u;
    }
    __syncthreads();
    if (last_flag) {
        __threadfence();
        float acc2 = 0.f;
        for (int i = tid; i < N_TOT; i += 256)
            acc2 += __logf(atomicAdd(&row_sums[i], 0.0f));   // coherent read
        #pragma unroll
        for (int m = 1; m < 64; m <<= 1) acc2 += __shfl_xor(acc2, m, 64);
        float* sred = (float*)smem;   // LDS tiles dead by now
        if (lane == 0) sred[w] = acc2;
        __syncthreads();
        if (tid == 0) {
            const float logsum = sred[0] + sred[1] + sred[2] + sred[3];
            const float pt = atomicAdd(pos_total, 0.0f);
            out[0] = INV_TAU + (logsum - pt) * (1.0f / (float)N_TOT);
        }
    }
}

extern "C" void kernel_launch(void* const* d_in, const int* in_sizes, int n_in,
                              void* d_out, int out_size, void* d_ws, size_t ws_size,
                              hipStream_t stream) {
    const float* anchor   = (const float*)d_in[0];
    const float* positive = (const float*)d_in[1];
    float* out = (float*)d_out;

    char* ws = (char*)d_ws;
    __bf16*   z         = (__bf16*)ws;                         // 8 MB
    float*    row_sums  = (float*)(ws + 8388608);              // 32 KB
    float*    pos_total = (float*)(ws + 8388608 + 32768);      // 4 B
    unsigned* counter   = (unsigned*)(ws + 8388608 + 32768 + 256);

    knorm<<<N_TOT / 4, 256, 0, stream>>>(anchor, positive, z, row_sums, pos_total, counter);
    ksim<<<NBLK, 256, 0, stream>>>(z, row_sums, pos_total, counter, out);
}